// Round 1
// baseline (443.102 us; speedup 1.0000x reference)
//
#include <hip/hip_runtime.h>

#define NB 8
#define CC 256
#define HH 8
#define DD 32
#define LL 4096

__device__ __forceinline__ float4 ld4(const float* p) { return *(const float4*)p; }

// ---------------------------------------------------------------------------
// Kernel 1: qkv = x^T @ w_qkv^T + b_qkv, scattered into q/k/v as [N,H,L,D]
// x is [N,C,L] (K-major for this GEMM). 64x64 tile, BK=16, 4x4 per thread.
// ---------------------------------------------------------------------------
__global__ __launch_bounds__(256) void gemm_qkv_k(
    const float* __restrict__ x, const float* __restrict__ wqkv,
    const float* __restrict__ bqkv,
    float* __restrict__ q, float* __restrict__ k, float* __restrict__ v)
{
    __shared__ float As[16][64];   // [c][l]
    __shared__ float Bs[16][68];   // [c][j], padded (2-way write alias is free)
    const int n  = blockIdx.z;
    const int l0 = blockIdx.x * 64;
    const int j0 = blockIdx.y * 64;
    const int tid = threadIdx.x;
    const int tx = tid & 15;       // l-group
    const int ty = tid >> 4;       // j-group
    const float* xn = x + (size_t)n * CC * LL;

    const int la_r = tid >> 4;         // 0..15  (c row of A tile)
    const int la_c = (tid & 15) * 4;   // l col
    const int lb_j = tid >> 2;         // 0..63  (j row of W tile)
    const int lb_c = (tid & 3) * 4;    // c col

    float acc[4][4] = {};

    for (int c0 = 0; c0 < CC; c0 += 16) {
        float4 a4 = ld4(xn + (size_t)(c0 + la_r) * LL + (l0 + la_c));
        float4 b4 = ld4(wqkv + (size_t)(j0 + lb_j) * CC + (c0 + lb_c));
        *(float4*)&As[la_r][la_c] = a4;
        Bs[lb_c + 0][lb_j] = b4.x;
        Bs[lb_c + 1][lb_j] = b4.y;
        Bs[lb_c + 2][lb_j] = b4.z;
        Bs[lb_c + 3][lb_j] = b4.w;
        __syncthreads();
#pragma unroll
        for (int cc = 0; cc < 16; ++cc) {
            float4 a = ld4(&As[cc][tx * 4]);
            float4 b = ld4(&Bs[cc][ty * 4]);
            float av[4] = {a.x, a.y, a.z, a.w};
            float bv[4] = {b.x, b.y, b.z, b.w};
#pragma unroll
            for (int i = 0; i < 4; ++i)
#pragma unroll
                for (int jj = 0; jj < 4; ++jj)
                    acc[i][jj] += av[i] * bv[jj];
        }
        __syncthreads();
    }

#pragma unroll
    for (int jj = 0; jj < 4; ++jj) {
        int j = j0 + ty * 4 + jj;               // 0..767
        float bias = bqkv[j];
        int s  = j >> 8;                        // 0=q 1=k 2=v
        int hh = (j >> 5) & 7;
        int d  = j & 31;
        float* dst = (s == 0) ? q : ((s == 1) ? k : v);
        dst += (size_t)(n * HH + hh) * LL * DD + d;
#pragma unroll
        for (int i = 0; i < 4; ++i) {
            int l = l0 + tx * 4 + i;
            dst[(size_t)l * DD] = acc[i][jj] + bias;
        }
    }
}

// ---------------------------------------------------------------------------
// Kernel 2: in-place L2 norm of q and k over D=32 (no eps, per reference)
// ---------------------------------------------------------------------------
__global__ __launch_bounds__(256) void l2norm_k(float* __restrict__ q, float* __restrict__ k)
{
    const int R = NB * HH * LL;                 // 262144 rows per tensor
    int row = blockIdx.x * 8 + (threadIdx.x >> 5);
    int e = threadIdx.x & 31;
    float* base;
    int r;
    if (row < R) { base = q; r = row; } else { base = k; r = row - R; }
    size_t idx = (size_t)r * DD + e;
    float val = base[idx];
    float ss = val * val;
#pragma unroll
    for (int off = 16; off; off >>= 1) ss += __shfl_xor(ss, off, 32);
    base[idx] = val * rsqrtf(ss);
}

// ---------------------------------------------------------------------------
// Kernel 3: attn[n,h,d,e] = sum_l k[n,h,l,d] * v[n,h,l,e]  (32x32, K=4096)
// One wave processes 128 tokens with a 4x4 register tile per lane.
// ---------------------------------------------------------------------------
__global__ __launch_bounds__(256) void attn_k(
    const float* __restrict__ k, const float* __restrict__ v, float* __restrict__ attn)
{
    __shared__ float red[4][1024];
    const int nh = blockIdx.y;
    const int wv = threadIdx.x >> 6;
    const int lane = threadIdx.x & 63;
    const int eg = lane & 7;      // e base = eg*4
    const int dg = lane >> 3;     // d base = dg*4
    const int l0 = blockIdx.x * 512 + wv * 128;
    const float* kb = k + (size_t)nh * LL * DD;
    const float* vb = v + (size_t)nh * LL * DD;
    float acc[4][4] = {};
#pragma unroll 4
    for (int l = l0; l < l0 + 128; ++l) {
        float4 k4 = ld4(kb + (size_t)l * DD + dg * 4);
        float4 v4 = ld4(vb + (size_t)l * DD + eg * 4);
        float ka[4] = {k4.x, k4.y, k4.z, k4.w};
        float va[4] = {v4.x, v4.y, v4.z, v4.w};
#pragma unroll
        for (int dp = 0; dp < 4; ++dp)
#pragma unroll
            for (int ep = 0; ep < 4; ++ep)
                acc[dp][ep] += ka[dp] * va[ep];
    }
#pragma unroll
    for (int dp = 0; dp < 4; ++dp)
#pragma unroll
        for (int ep = 0; ep < 4; ++ep)
            red[wv][(dg * 4 + dp) * 32 + eg * 4 + ep] = acc[dp][ep];
    __syncthreads();
    float* ap = attn + (size_t)nh * 1024;
    for (int i = threadIdx.x; i < 1024; i += 256)
        atomicAdd(&ap[i], red[0][i] + red[1][i] + red[2][i] + red[3][i]);
}

// ---------------------------------------------------------------------------
// Kernel 4: mid[n,l,h*32+e] = l2norm_e(0.5*v + (1/pi)*q@attn) + dconv(v)
// Block: 8 tokens x 32 lanes; attn tile + q rows staged in LDS.
// ---------------------------------------------------------------------------
__global__ __launch_bounds__(256) void mid_k(
    const float* __restrict__ q, const float* __restrict__ v,
    const float* __restrict__ attn, const float* __restrict__ wd,
    float* __restrict__ mid)
{
    __shared__ float at[32][32];
    __shared__ float qs[8][32];
    __shared__ float wds[9];
    const int nh = blockIdx.y;
    const int n = nh >> 3, hh = nh & 7;
    const int tid = threadIdx.x;
    for (int i = tid; i < 1024; i += 256)
        at[i >> 5][i & 31] = attn[(size_t)nh * 1024 + i];
    if (tid < 9) wds[tid] = wd[hh * 9 + tid];
    const int row = tid >> 5;
    const int e = tid & 31;
    const int l = blockIdx.x * 8 + row;
    const float* vb = v + (size_t)nh * LL * DD;
    qs[row][e] = q[((size_t)nh * LL + l) * DD + e];
    __syncthreads();
    float s = 0.f;
#pragma unroll
    for (int d4 = 0; d4 < 8; ++d4) {
        float4 q4 = ld4(&qs[row][d4 * 4]);
        s += q4.x * at[d4 * 4 + 0][e];
        s += q4.y * at[d4 * 4 + 1][e];
        s += q4.z * at[d4 * 4 + 2][e];
        s += q4.w * at[d4 * 4 + 3][e];
    }
    float t = 0.5f * vb[(size_t)l * DD + e] + 0.31830988618379067f * s;
    float ss = t * t;
#pragma unroll
    for (int off = 16; off; off >>= 1) ss += __shfl_xor(ss, off, 32);
    float o = t * rsqrtf(ss);
    float dv = 0.f;
#pragma unroll
    for (int r = 0; r < 9; ++r) {
        int lr = l + r - 4;
        if (lr >= 0 && lr < LL) dv += wds[r] * vb[(size_t)lr * DD + e];
    }
    mid[((size_t)n * LL + l) * CC + hh * DD + e] = o + dv;
}

// ---------------------------------------------------------------------------
// Kernel 5: out[n,c,l] = sum_c' mid[n,l,c'] * w_proj[c,c'] + b_proj[c]
// Same 64x64 tile; writes the transposed [N,C,h,w] layout with float4 stores.
// ---------------------------------------------------------------------------
__global__ __launch_bounds__(256) void gemm_proj_k(
    const float* __restrict__ mid, const float* __restrict__ wp,
    const float* __restrict__ bp, float* __restrict__ out)
{
    __shared__ float As[16][68];   // [c][l] transposed in, padded
    __shared__ float Bs[16][68];   // [c][j]
    const int n  = blockIdx.z;
    const int l0 = blockIdx.x * 64;
    const int j0 = blockIdx.y * 64;
    const int tid = threadIdx.x;
    const int tx = tid & 15, ty = tid >> 4;
    const float* mb = mid + (size_t)n * LL * CC;
    const int lr = tid >> 2;          // 0..63 (row: l for A, j for B)
    const int lc = (tid & 3) * 4;     // c offset
    float acc[4][4] = {};
    for (int c0 = 0; c0 < CC; c0 += 16) {
        float4 a4 = ld4(mb + (size_t)(l0 + lr) * CC + c0 + lc);
        float4 b4 = ld4(wp + (size_t)(j0 + lr) * CC + c0 + lc);
        As[lc + 0][lr] = a4.x; As[lc + 1][lr] = a4.y;
        As[lc + 2][lr] = a4.z; As[lc + 3][lr] = a4.w;
        Bs[lc + 0][lr] = b4.x; Bs[lc + 1][lr] = b4.y;
        Bs[lc + 2][lr] = b4.z; Bs[lc + 3][lr] = b4.w;
        __syncthreads();
#pragma unroll
        for (int cc = 0; cc < 16; ++cc) {
            float4 a = ld4(&As[cc][tx * 4]);
            float4 b = ld4(&Bs[cc][ty * 4]);
            float av[4] = {a.x, a.y, a.z, a.w};
            float bv[4] = {b.x, b.y, b.z, b.w};
#pragma unroll
            for (int i = 0; i < 4; ++i)
#pragma unroll
                for (int jj = 0; jj < 4; ++jj)
                    acc[i][jj] += av[i] * bv[jj];
        }
        __syncthreads();
    }
#pragma unroll
    for (int jj = 0; jj < 4; ++jj) {
        int j = j0 + ty * 4 + jj;
        float bias = bp[j];
        float* ob = out + ((size_t)n * CC + j) * LL + l0 + tx * 4;
        float4 o4 = {acc[0][jj] + bias, acc[1][jj] + bias,
                     acc[2][jj] + bias, acc[3][jj] + bias};
        *(float4*)ob = o4;
    }
}

// ---------------------------------------------------------------------------
extern "C" void kernel_launch(void* const* d_in, const int* in_sizes, int n_in,
                              void* d_out, int out_size, void* d_ws, size_t ws_size,
                              hipStream_t stream)
{
    const float* x     = (const float*)d_in[0];
    const float* wqkv  = (const float*)d_in[1];
    const float* bqkv  = (const float*)d_in[2];
    const float* wproj = (const float*)d_in[3];
    const float* bproj = (const float*)d_in[4];
    const float* wd    = (const float*)d_in[5];
    float* out = (float*)d_out;

    float* ws = (float*)d_ws;
    const size_t QKV = (size_t)NB * HH * LL * DD;   // 8388608 floats
    float* q    = ws;
    float* k    = q + QKV;
    float* v    = k + QKV;
    float* attn = v + QKV;                           // 65536 floats
    float* mid  = attn + (size_t)NB * HH * DD * DD;  // 8388608 floats

    hipMemsetAsync(attn, 0, (size_t)NB * HH * DD * DD * sizeof(float), stream);

    gemm_qkv_k<<<dim3(64, 12, 8), 256, 0, stream>>>(x, wqkv, bqkv, q, k, v);
    l2norm_k<<<65536, 256, 0, stream>>>(q, k);
    attn_k<<<dim3(8, 64), 256, 0, stream>>>(k, v, attn);
    mid_k<<<dim3(512, 64), 256, 0, stream>>>(q, v, attn, wd, mid);
    gemm_proj_k<<<dim3(64, 4, 8), 256, 0, stream>>>(mid, wproj, bproj, out);
}

// Round 2
// 299.780 us; speedup vs baseline: 1.4781x; 1.4781x over previous
//
#include <hip/hip_runtime.h>

#define NB 8
#define CC 256
#define HH 8
#define DD 32
#define LL 4096

typedef short v8s __attribute__((ext_vector_type(8)));
typedef float v4f __attribute__((ext_vector_type(4)));
typedef unsigned short v8u __attribute__((ext_vector_type(8)));

__device__ __forceinline__ float4 ld4(const float* p) { return *(const float4*)p; }

// round-to-nearest-even fp32 -> bf16 (as ushort)
__device__ __forceinline__ unsigned short f2bf(float f) {
    union { float f; unsigned int u; } v; v.f = f;
    unsigned int r = (v.u + 0x7FFFu + ((v.u >> 16) & 1u)) >> 16;
    return (unsigned short)r;
}

// ---------------------------------------------------------------------------
// Convert fp32 -> bf16 (weights)
// ---------------------------------------------------------------------------
__global__ __launch_bounds__(256) void cvt_k(const float* __restrict__ s,
                                             unsigned short* __restrict__ d, int n)
{
    int i = blockIdx.x * 256 + threadIdx.x;
    if (i < n) d[i] = f2bf(s[i]);
}

// ---------------------------------------------------------------------------
// Transpose x[N,C,L] fp32 -> xb[N,L,C] bf16.  One block = 32 l-rows (full C),
// so the block's output is 16 KB fully contiguous -> coalesced v8u stores.
// ---------------------------------------------------------------------------
#define PADC 264
__global__ __launch_bounds__(256) void transpose_x_k(
    const float* __restrict__ x, unsigned short* __restrict__ xb)
{
    __shared__ unsigned short t[32][PADC];
    const int n = blockIdx.y;
    const int l0 = blockIdx.x * 32;
    const float* xn = x + (size_t)n * CC * LL;
    const int lam = threadIdx.x & 31;
    const int cb = threadIdx.x >> 5;      // 0..7
#pragma unroll
    for (int i = 0; i < 32; ++i) {
        int c = cb * 32 + i;
        t[lam][c] = f2bf(xn[(size_t)c * LL + l0 + lam]);   // coalesced reads
    }
    __syncthreads();
    unsigned short* dst = xb + ((size_t)n * LL + l0) * CC;  // 8192 ushorts contiguous
    const int tid = threadIdx.x;
#pragma unroll
    for (int i = 0; i < 4; ++i) {
        int f = i * 2048 + tid * 8;
        int lr = f >> 8;
        int c2 = f & 255;
        v8u val = *(const v8u*)&t[lr][c2];   // 16-B aligned (PADC*2 % 16 == 0)
        *(v8u*)(dst + f) = val;              // fully coalesced store
    }
}

// ---------------------------------------------------------------------------
// Kernel 1: MFMA qkv GEMM.  C[l][j] = sum_c xb[l][c]*wq[j][c] + b[j]
// 128x128 tile / block, 4 waves (2x2), 4x4 16x16x32 fragments per wave.
// Direct global fragment loads (both operands k-contiguous); no LDS.
// ---------------------------------------------------------------------------
__global__ __launch_bounds__(256) void gemm_qkv_mfma(
    const unsigned short* __restrict__ xb, const unsigned short* __restrict__ wqb,
    const float* __restrict__ bqkv,
    float* __restrict__ q, float* __restrict__ k, float* __restrict__ v)
{
    const int n  = blockIdx.z;
    const int l0 = blockIdx.x * 128;
    const int j0 = blockIdx.y * 128;
    const int tid = threadIdx.x;
    const int lane = tid & 63, wave = tid >> 6;
    const int wr = wave >> 1, wc = wave & 1;
    const int r = lane & 15, quad = lane >> 4;

    const unsigned short* abase = xb + (size_t)n * LL * CC
                                + (size_t)(l0 + wr * 64 + r) * CC + quad * 8;
    const unsigned short* bbase = wqb + (size_t)(j0 + wc * 64 + r) * CC + quad * 8;

    v4f acc[4][4];
#pragma unroll
    for (int mi = 0; mi < 4; ++mi)
#pragma unroll
        for (int nj = 0; nj < 4; ++nj) acc[mi][nj] = (v4f)(0.f);

    for (int c0 = 0; c0 < CC; c0 += 32) {
        v8s a[4], b[4];
#pragma unroll
        for (int mi = 0; mi < 4; ++mi) a[mi] = *(const v8s*)(abase + (size_t)mi * 16 * CC + c0);
#pragma unroll
        for (int nj = 0; nj < 4; ++nj) b[nj] = *(const v8s*)(bbase + (size_t)nj * 16 * CC + c0);
#pragma unroll
        for (int mi = 0; mi < 4; ++mi)
#pragma unroll
            for (int nj = 0; nj < 4; ++nj)
                acc[mi][nj] = __builtin_amdgcn_mfma_f32_16x16x32_bf16(a[mi], b[nj], acc[mi][nj], 0, 0, 0);
    }

    // D mapping: col = lane&15, row = quad*4 + reg
#pragma unroll
    for (int nj = 0; nj < 4; ++nj) {
        int j = j0 + wc * 64 + nj * 16 + r;     // 0..767
        float bias = bqkv[j];
        int s  = j >> 8;
        int hh = (j >> 5) & 7;
        int d  = j & 31;
        float* dst = (s == 0 ? q : (s == 1 ? k : v))
                   + (size_t)(n * HH + hh) * LL * DD + d;
#pragma unroll
        for (int mi = 0; mi < 4; ++mi)
#pragma unroll
            for (int reg = 0; reg < 4; ++reg) {
                int l = l0 + wr * 64 + mi * 16 + quad * 4 + reg;
                dst[(size_t)l * DD] = acc[mi][nj][reg] + bias;
            }
    }
}

// ---------------------------------------------------------------------------
// Kernel 2: in-place L2 norm of q and k over D=32
// ---------------------------------------------------------------------------
__global__ __launch_bounds__(256) void l2norm_k(float* __restrict__ q, float* __restrict__ k)
{
    const int R = NB * HH * LL;
    int row = blockIdx.x * 8 + (threadIdx.x >> 5);
    int e = threadIdx.x & 31;
    float* base;
    int r;
    if (row < R) { base = q; r = row; } else { base = k; r = row - R; }
    size_t idx = (size_t)r * DD + e;
    float val = base[idx];
    float ss = val * val;
#pragma unroll
    for (int off = 16; off; off >>= 1) ss += __shfl_xor(ss, off, 32);
    base[idx] = val * rsqrtf(ss);
}

// ---------------------------------------------------------------------------
// Kernel 3: attn[n,h,d,e] = sum_l k[n,h,l,d] * v[n,h,l,e]
// ---------------------------------------------------------------------------
__global__ __launch_bounds__(256) void attn_k(
    const float* __restrict__ k, const float* __restrict__ v, float* __restrict__ attn)
{
    __shared__ float red[4][1024];
    const int nh = blockIdx.y;
    const int wv = threadIdx.x >> 6;
    const int lane = threadIdx.x & 63;
    const int eg = lane & 7;
    const int dg = lane >> 3;
    const int l0 = blockIdx.x * 512 + wv * 128;
    const float* kb = k + (size_t)nh * LL * DD;
    const float* vb = v + (size_t)nh * LL * DD;
    float acc[4][4] = {};
#pragma unroll 4
    for (int l = l0; l < l0 + 128; ++l) {
        float4 k4 = ld4(kb + (size_t)l * DD + dg * 4);
        float4 v4 = ld4(vb + (size_t)l * DD + eg * 4);
        float ka[4] = {k4.x, k4.y, k4.z, k4.w};
        float va[4] = {v4.x, v4.y, v4.z, v4.w};
#pragma unroll
        for (int dp = 0; dp < 4; ++dp)
#pragma unroll
            for (int ep = 0; ep < 4; ++ep)
                acc[dp][ep] += ka[dp] * va[ep];
    }
#pragma unroll
    for (int dp = 0; dp < 4; ++dp)
#pragma unroll
        for (int ep = 0; ep < 4; ++ep)
            red[wv][(dg * 4 + dp) * 32 + eg * 4 + ep] = acc[dp][ep];
    __syncthreads();
    float* ap = attn + (size_t)nh * 1024;
    for (int i = threadIdx.x; i < 1024; i += 256)
        atomicAdd(&ap[i], red[0][i] + red[1][i] + red[2][i] + red[3][i]);
}

// ---------------------------------------------------------------------------
// Kernel 4: midb[n,l,h*32+e] = bf16( l2norm_e(0.5*v + (1/pi)*q@attn) + dconv(v) )
// ---------------------------------------------------------------------------
__global__ __launch_bounds__(256) void mid_k(
    const float* __restrict__ q, const float* __restrict__ v,
    const float* __restrict__ attn, const float* __restrict__ wd,
    unsigned short* __restrict__ midb)
{
    __shared__ float at[32][32];
    __shared__ float qs[8][32];
    __shared__ float wds[9];
    const int nh = blockIdx.y;
    const int n = nh >> 3, hh = nh & 7;
    const int tid = threadIdx.x;
    for (int i = tid; i < 1024; i += 256)
        at[i >> 5][i & 31] = attn[(size_t)nh * 1024 + i];
    if (tid < 9) wds[tid] = wd[hh * 9 + tid];
    const int row = tid >> 5;
    const int e = tid & 31;
    const int l = blockIdx.x * 8 + row;
    const float* vb = v + (size_t)nh * LL * DD;
    qs[row][e] = q[((size_t)nh * LL + l) * DD + e];
    __syncthreads();
    float s = 0.f;
#pragma unroll
    for (int d4 = 0; d4 < 8; ++d4) {
        float4 q4 = ld4(&qs[row][d4 * 4]);
        s += q4.x * at[d4 * 4 + 0][e];
        s += q4.y * at[d4 * 4 + 1][e];
        s += q4.z * at[d4 * 4 + 2][e];
        s += q4.w * at[d4 * 4 + 3][e];
    }
    float t = 0.5f * vb[(size_t)l * DD + e] + 0.31830988618379067f * s;
    float ss = t * t;
#pragma unroll
    for (int off = 16; off; off >>= 1) ss += __shfl_xor(ss, off, 32);
    float o = t * rsqrtf(ss);
    float dv = 0.f;
#pragma unroll
    for (int r = 0; r < 9; ++r) {
        int lr = l + r - 4;
        if (lr >= 0 && lr < LL) dv += wds[r] * vb[(size_t)lr * DD + e];
    }
    midb[((size_t)n * LL + l) * CC + hh * DD + e] = f2bf(o + dv);
}

// ---------------------------------------------------------------------------
// Kernel 5: MFMA proj GEMM, roles swapped (M=j, N=l) so stores are coalesced
// along l.  out[n,j,l] = sum_c mid[l][c]*wp[j][c] + bp[j]
// ---------------------------------------------------------------------------
__global__ __launch_bounds__(256) void gemm_proj_mfma(
    const unsigned short* __restrict__ midb, const unsigned short* __restrict__ wpb,
    const float* __restrict__ bp, float* __restrict__ out)
{
    const int n  = blockIdx.z;
    const int j0 = blockIdx.x * 128;
    const int l0 = blockIdx.y * 128;
    const int tid = threadIdx.x;
    const int lane = tid & 63, wave = tid >> 6;
    const int wr = wave >> 1, wc = wave & 1;
    const int r = lane & 15, quad = lane >> 4;

    const unsigned short* abase = wpb + (size_t)(j0 + wr * 64 + r) * CC + quad * 8;
    const unsigned short* bbase = midb + (size_t)n * LL * CC
                                + (size_t)(l0 + wc * 64 + r) * CC + quad * 8;

    v4f acc[4][4];
#pragma unroll
    for (int mi = 0; mi < 4; ++mi)
#pragma unroll
        for (int nj = 0; nj < 4; ++nj) acc[mi][nj] = (v4f)(0.f);

    for (int c0 = 0; c0 < CC; c0 += 32) {
        v8s a[4], b[4];
#pragma unroll
        for (int mi = 0; mi < 4; ++mi) a[mi] = *(const v8s*)(abase + (size_t)mi * 16 * CC + c0);
#pragma unroll
        for (int nj = 0; nj < 4; ++nj) b[nj] = *(const v8s*)(bbase + (size_t)nj * 16 * CC + c0);
#pragma unroll
        for (int mi = 0; mi < 4; ++mi)
#pragma unroll
            for (int nj = 0; nj < 4; ++nj)
                acc[mi][nj] = __builtin_amdgcn_mfma_f32_16x16x32_bf16(a[mi], b[nj], acc[mi][nj], 0, 0, 0);
    }

    // rows = j (quad*4+reg), cols = l (lane&15) -> coalesced along l
#pragma unroll
    for (int mi = 0; mi < 4; ++mi)
#pragma unroll
        for (int reg = 0; reg < 4; ++reg) {
            int j = j0 + wr * 64 + mi * 16 + quad * 4 + reg;
            float bias = bp[j];
#pragma unroll
            for (int nj = 0; nj < 4; ++nj) {
                int l = l0 + wc * 64 + nj * 16 + r;
                out[((size_t)n * CC + j) * LL + l] = acc[mi][nj][reg] + bias;
            }
        }
}

// ---------------------------------------------------------------------------
extern "C" void kernel_launch(void* const* d_in, const int* in_sizes, int n_in,
                              void* d_out, int out_size, void* d_ws, size_t ws_size,
                              hipStream_t stream)
{
    const float* x     = (const float*)d_in[0];
    const float* wqkv  = (const float*)d_in[1];
    const float* bqkv  = (const float*)d_in[2];
    const float* wproj = (const float*)d_in[3];
    const float* bproj = (const float*)d_in[4];
    const float* wd    = (const float*)d_in[5];
    float* out = (float*)d_out;

    float* ws = (float*)d_ws;
    const size_t QKV = (size_t)NB * HH * LL * DD;   // 8388608 floats
    float* q    = ws;
    float* k    = q + QKV;
    float* v    = k + QKV;
    float* attn = v + QKV;                                   // 65536 floats
    unsigned short* xb  = (unsigned short*)(attn + (size_t)NB * HH * DD * DD);
    unsigned short* midb = xb;                               // live ranges disjoint
    unsigned short* wqb = xb + (size_t)NB * LL * CC;         // 196608 ushorts
    unsigned short* wpb = wqb + 3 * CC * CC;                 // 65536 ushorts

    hipMemsetAsync(attn, 0, (size_t)NB * HH * DD * DD * sizeof(float), stream);

    cvt_k<<<768, 256, 0, stream>>>(wqkv, wqb, 3 * CC * CC);
    cvt_k<<<256, 256, 0, stream>>>(wproj, wpb, CC * CC);
    transpose_x_k<<<dim3(128, 8), 256, 0, stream>>>(x, xb);
    gemm_qkv_mfma<<<dim3(32, 6, 8), 256, 0, stream>>>(xb, wqb, bqkv, q, k, v);
    l2norm_k<<<65536, 256, 0, stream>>>(q, k);
    attn_k<<<dim3(8, 64), 256, 0, stream>>>(k, v, attn);
    mid_k<<<dim3(512, 64), 256, 0, stream>>>(q, v, attn, wd, midb);
    gemm_proj_mfma<<<dim3(2, 32, 8), 256, 0, stream>>>(midb, wpb, bproj, out);
}

// Round 3
// 239.328 us; speedup vs baseline: 1.8514x; 1.2526x over previous
//
#include <hip/hip_runtime.h>

#define NB 8
#define CC 256
#define HH 8
#define DD 32
#define LL 4096

typedef short v8s __attribute__((ext_vector_type(8)));
typedef float v4f __attribute__((ext_vector_type(4)));
typedef unsigned short v8u __attribute__((ext_vector_type(8)));

__device__ __forceinline__ float4 ld4(const float* p) { return *(const float4*)p; }

// round-to-nearest-even fp32 -> bf16 (as ushort)
__device__ __forceinline__ unsigned short f2bf(float f) {
    union { float f; unsigned int u; } v; v.f = f;
    unsigned int r = (v.u + 0x7FFFu + ((v.u >> 16) & 1u)) >> 16;
    return (unsigned short)r;
}

// ---------------------------------------------------------------------------
// Convert fp32 -> bf16 (weights)
// ---------------------------------------------------------------------------
__global__ __launch_bounds__(256) void cvt_k(const float* __restrict__ s,
                                             unsigned short* __restrict__ d, int n)
{
    int i = blockIdx.x * 256 + threadIdx.x;
    if (i < n) d[i] = f2bf(s[i]);
}

// ---------------------------------------------------------------------------
// Transpose x[N,C,L] fp32 -> xb[N,L,C] bf16.
// ---------------------------------------------------------------------------
#define PADC 264
__global__ __launch_bounds__(256) void transpose_x_k(
    const float* __restrict__ x, unsigned short* __restrict__ xb)
{
    __shared__ unsigned short t[32][PADC];
    const int n = blockIdx.y;
    const int l0 = blockIdx.x * 32;
    const float* xn = x + (size_t)n * CC * LL;
    const int lam = threadIdx.x & 31;
    const int cb = threadIdx.x >> 5;
#pragma unroll
    for (int i = 0; i < 32; ++i) {
        int c = cb * 32 + i;
        t[lam][c] = f2bf(xn[(size_t)c * LL + l0 + lam]);
    }
    __syncthreads();
    unsigned short* dst = xb + ((size_t)n * LL + l0) * CC;
    const int tid = threadIdx.x;
#pragma unroll
    for (int i = 0; i < 4; ++i) {
        int f = i * 2048 + tid * 8;
        int lr = f >> 8;
        int c2 = f & 255;
        v8u val = *(const v8u*)&t[lr][c2];
        *(v8u*)(dst + f) = val;
    }
}

// ---------------------------------------------------------------------------
// Kernel 1: MFMA qkv GEMM with FUSED L2-norm for q/k tiles.
// C[l][j] = sum_c xb[l][c]*wq[j][c] + b[j]; then q,k rows normalized over
// their head's 32 columns (nj fragment pairs x 16 lanes, shfl_xor reduce).
// ---------------------------------------------------------------------------
__global__ __launch_bounds__(256) void gemm_qkv_mfma(
    const unsigned short* __restrict__ xb, const unsigned short* __restrict__ wqb,
    const float* __restrict__ bqkv,
    float* __restrict__ q, float* __restrict__ k, float* __restrict__ v)
{
    const int n  = blockIdx.z;
    const int l0 = blockIdx.x * 128;
    const int j0 = blockIdx.y * 128;
    const int tid = threadIdx.x;
    const int lane = tid & 63, wave = tid >> 6;
    const int wr = wave >> 1, wc = wave & 1;
    const int r = lane & 15, quad = lane >> 4;

    const unsigned short* abase = xb + (size_t)n * LL * CC
                                + (size_t)(l0 + wr * 64 + r) * CC + quad * 8;
    const unsigned short* bbase = wqb + (size_t)(j0 + wc * 64 + r) * CC + quad * 8;

    v4f acc[4][4];
#pragma unroll
    for (int mi = 0; mi < 4; ++mi)
#pragma unroll
        for (int nj = 0; nj < 4; ++nj) acc[mi][nj] = (v4f)(0.f);

    for (int c0 = 0; c0 < CC; c0 += 32) {
        v8s a[4], b[4];
#pragma unroll
        for (int mi = 0; mi < 4; ++mi) a[mi] = *(const v8s*)(abase + (size_t)mi * 16 * CC + c0);
#pragma unroll
        for (int nj = 0; nj < 4; ++nj) b[nj] = *(const v8s*)(bbase + (size_t)nj * 16 * CC + c0);
#pragma unroll
        for (int mi = 0; mi < 4; ++mi)
#pragma unroll
            for (int nj = 0; nj < 4; ++nj)
                acc[mi][nj] = __builtin_amdgcn_mfma_f32_16x16x32_bf16(a[mi], b[nj], acc[mi][nj], 0, 0, 0);
    }

    // D mapping: col = lane&15 (j), row = quad*4 + reg (l)
    const int s = j0 >> 8;                    // 0=q 1=k 2=v, block-uniform
    float* base = (s == 0 ? q : (s == 1 ? k : v));
    float bias[4];
    float* dstp[4];
#pragma unroll
    for (int nj = 0; nj < 4; ++nj) {
        int j = j0 + wc * 64 + nj * 16 + r;
        bias[nj] = bqkv[j];
        int hh = (j >> 5) & 7;
        int d  = j & 31;
        dstp[nj] = base + (size_t)(n * HH + hh) * LL * DD + d;
    }

    if (s < 2) {
        // fused L2 norm: head0 = fragments nj 0,1; head1 = nj 2,3
#pragma unroll
        for (int mi = 0; mi < 4; ++mi)
#pragma unroll
            for (int reg = 0; reg < 4; ++reg) {
                size_t l = (size_t)(l0 + wr * 64 + mi * 16 + quad * 4 + reg);
                float v0 = acc[mi][0][reg] + bias[0];
                float v1 = acc[mi][1][reg] + bias[1];
                float v2 = acc[mi][2][reg] + bias[2];
                float v3 = acc[mi][3][reg] + bias[3];
                float ss0 = v0 * v0 + v1 * v1;
                float ss1 = v2 * v2 + v3 * v3;
#pragma unroll
                for (int m = 1; m < 16; m <<= 1) {
                    ss0 += __shfl_xor(ss0, m);
                    ss1 += __shfl_xor(ss1, m);
                }
                float r0 = rsqrtf(ss0), r1 = rsqrtf(ss1);
                dstp[0][l * DD] = v0 * r0;
                dstp[1][l * DD] = v1 * r0;
                dstp[2][l * DD] = v2 * r1;
                dstp[3][l * DD] = v3 * r1;
            }
    } else {
#pragma unroll
        for (int mi = 0; mi < 4; ++mi)
#pragma unroll
            for (int reg = 0; reg < 4; ++reg) {
                size_t l = (size_t)(l0 + wr * 64 + mi * 16 + quad * 4 + reg);
#pragma unroll
                for (int nj = 0; nj < 4; ++nj)
                    dstp[nj][l * DD] = acc[mi][nj][reg] + bias[nj];
            }
    }
}

// ---------------------------------------------------------------------------
// Kernel 3: attn[n,h,d,e] = sum_l k[n,h,l,d] * v[n,h,l,e]
// ---------------------------------------------------------------------------
__global__ __launch_bounds__(256) void attn_k(
    const float* __restrict__ k, const float* __restrict__ v, float* __restrict__ attn)
{
    __shared__ float red[4][1024];
    const int nh = blockIdx.y;
    const int wv = threadIdx.x >> 6;
    const int lane = threadIdx.x & 63;
    const int eg = lane & 7;
    const int dg = lane >> 3;
    const int l0 = blockIdx.x * 512 + wv * 128;
    const float* kb = k + (size_t)nh * LL * DD;
    const float* vb = v + (size_t)nh * LL * DD;
    float acc[4][4] = {};
#pragma unroll 4
    for (int l = l0; l < l0 + 128; ++l) {
        float4 k4 = ld4(kb + (size_t)l * DD + dg * 4);
        float4 v4 = ld4(vb + (size_t)l * DD + eg * 4);
        float ka[4] = {k4.x, k4.y, k4.z, k4.w};
        float va[4] = {v4.x, v4.y, v4.z, v4.w};
#pragma unroll
        for (int dp = 0; dp < 4; ++dp)
#pragma unroll
            for (int ep = 0; ep < 4; ++ep)
                acc[dp][ep] += ka[dp] * va[ep];
    }
#pragma unroll
    for (int dp = 0; dp < 4; ++dp)
#pragma unroll
        for (int ep = 0; ep < 4; ++ep)
            red[wv][(dg * 4 + dp) * 32 + eg * 4 + ep] = acc[dp][ep];
    __syncthreads();
    float* ap = attn + (size_t)nh * 1024;
    for (int i = threadIdx.x; i < 1024; i += 256)
        atomicAdd(&ap[i], red[0][i] + red[1][i] + red[2][i] + red[3][i]);
}

// ---------------------------------------------------------------------------
// Kernel 4 (rewritten): one block = 256 tokens of one (n,h).
// v tile staged in LDS once; attn column held in 32 VGPRs per lane;
// q rows via broadcast float4 global loads. Norm over e = 32-lane shfl.
// ---------------------------------------------------------------------------
#define TOK 256
__global__ __launch_bounds__(256) void mid_k(
    const float* __restrict__ q, const float* __restrict__ v,
    const float* __restrict__ attn, const float* __restrict__ wd,
    unsigned short* __restrict__ midb)
{
    __shared__ float vt[TOK + 8][32];     // rows l0-4 .. l0+TOK+3
    const int nh = blockIdx.y;
    const int n = nh >> 3, hh = nh & 7;
    const int l0 = blockIdx.x * TOK;
    const int tid = threadIdx.x;
    const int row = tid >> 5;             // 0..7
    const int e = tid & 31;
    const float* vb = v + (size_t)nh * LL * DD;

    for (int f = tid; f < (TOK + 8) * 32; f += 256) {
        int rr = f >> 5, ee = f & 31;
        int l = l0 - 4 + rr;
        vt[rr][ee] = (l >= 0 && l < LL) ? vb[(size_t)l * DD + ee] : 0.f;
    }

    // attn column for this lane's e
    float atc[32];
    const float* ap = attn + (size_t)nh * 1024 + e;
#pragma unroll
    for (int d = 0; d < 32; ++d) atc[d] = ap[d * 32];

    float wc[9];
#pragma unroll
    for (int r9 = 0; r9 < 9; ++r9) wc[r9] = wd[hh * 9 + r9];

    __syncthreads();

    const float* qb = q + (size_t)nh * LL * DD;
    unsigned short* ob = midb + ((size_t)n * LL) * CC + hh * DD + e;

    for (int it = 0; it < TOK / 8; ++it) {
        int lr = it * 8 + row;            // local token index 0..255
        int l = l0 + lr;
        const float* qrow = qb + (size_t)l * DD;
        float s = 0.f;
#pragma unroll
        for (int d4 = 0; d4 < 8; ++d4) {
            float4 q4 = ld4(qrow + d4 * 4);   // broadcast within row-group
            s += q4.x * atc[d4 * 4 + 0];
            s += q4.y * atc[d4 * 4 + 1];
            s += q4.z * atc[d4 * 4 + 2];
            s += q4.w * atc[d4 * 4 + 3];
        }
        float t = 0.5f * vt[lr + 4][e] + 0.31830988618379067f * s;
        float ss = t * t;
#pragma unroll
        for (int off = 16; off; off >>= 1) ss += __shfl_xor(ss, off, 32);
        float o = t * rsqrtf(ss);
        float dv = 0.f;
#pragma unroll
        for (int r9 = 0; r9 < 9; ++r9) dv += wc[r9] * vt[lr + r9][e];
        ob[(size_t)l * CC] = f2bf(o + dv);
    }
}

// ---------------------------------------------------------------------------
// Kernel 5: MFMA proj GEMM (M=j, N=l), coalesced stores along l.
// ---------------------------------------------------------------------------
__global__ __launch_bounds__(256) void gemm_proj_mfma(
    const unsigned short* __restrict__ midb, const unsigned short* __restrict__ wpb,
    const float* __restrict__ bp, float* __restrict__ out)
{
    const int n  = blockIdx.z;
    const int j0 = blockIdx.x * 128;
    const int l0 = blockIdx.y * 128;
    const int tid = threadIdx.x;
    const int lane = tid & 63, wave = tid >> 6;
    const int wr = wave >> 1, wc = wave & 1;
    const int r = lane & 15, quad = lane >> 4;

    const unsigned short* abase = wpb + (size_t)(j0 + wr * 64 + r) * CC + quad * 8;
    const unsigned short* bbase = midb + (size_t)n * LL * CC
                                + (size_t)(l0 + wc * 64 + r) * CC + quad * 8;

    v4f acc[4][4];
#pragma unroll
    for (int mi = 0; mi < 4; ++mi)
#pragma unroll
        for (int nj = 0; nj < 4; ++nj) acc[mi][nj] = (v4f)(0.f);

    for (int c0 = 0; c0 < CC; c0 += 32) {
        v8s a[4], b[4];
#pragma unroll
        for (int mi = 0; mi < 4; ++mi) a[mi] = *(const v8s*)(abase + (size_t)mi * 16 * CC + c0);
#pragma unroll
        for (int nj = 0; nj < 4; ++nj) b[nj] = *(const v8s*)(bbase + (size_t)nj * 16 * CC + c0);
#pragma unroll
        for (int mi = 0; mi < 4; ++mi)
#pragma unroll
            for (int nj = 0; nj < 4; ++nj)
                acc[mi][nj] = __builtin_amdgcn_mfma_f32_16x16x32_bf16(a[mi], b[nj], acc[mi][nj], 0, 0, 0);
    }

#pragma unroll
    for (int mi = 0; mi < 4; ++mi)
#pragma unroll
        for (int reg = 0; reg < 4; ++reg) {
            int j = j0 + wr * 64 + mi * 16 + quad * 4 + reg;
            float bias = bp[j];
#pragma unroll
            for (int nj = 0; nj < 4; ++nj) {
                int l = l0 + wc * 64 + nj * 16 + r;
                out[((size_t)n * CC + j) * LL + l] = acc[mi][nj][reg] + bias;
            }
        }
}

// ---------------------------------------------------------------------------
extern "C" void kernel_launch(void* const* d_in, const int* in_sizes, int n_in,
                              void* d_out, int out_size, void* d_ws, size_t ws_size,
                              hipStream_t stream)
{
    const float* x     = (const float*)d_in[0];
    const float* wqkv  = (const float*)d_in[1];
    const float* bqkv  = (const float*)d_in[2];
    const float* wproj = (const float*)d_in[3];
    const float* bproj = (const float*)d_in[4];
    const float* wd    = (const float*)d_in[5];
    float* out = (float*)d_out;

    float* ws = (float*)d_ws;
    const size_t QKV = (size_t)NB * HH * LL * DD;
    float* q    = ws;
    float* k    = q + QKV;
    float* v    = k + QKV;
    float* attn = v + QKV;
    unsigned short* xb  = (unsigned short*)(attn + (size_t)NB * HH * DD * DD);
    unsigned short* midb = xb;                       // disjoint live ranges
    unsigned short* wqb = xb + (size_t)NB * LL * CC;
    unsigned short* wpb = wqb + 3 * CC * CC;

    hipMemsetAsync(attn, 0, (size_t)NB * HH * DD * DD * sizeof(float), stream);

    cvt_k<<<768, 256, 0, stream>>>(wqkv, wqb, 3 * CC * CC);
    cvt_k<<<256, 256, 0, stream>>>(wproj, wpb, CC * CC);
    transpose_x_k<<<dim3(128, 8), 256, 0, stream>>>(x, xb);
    gemm_qkv_mfma<<<dim3(32, 6, 8), 256, 0, stream>>>(xb, wqb, bqkv, q, k, v);
    attn_k<<<dim3(8, 64), 256, 0, stream>>>(k, v, attn);
    mid_k<<<dim3(LL / TOK, 64), 256, 0, stream>>>(q, v, attn, wd, midb);
    gemm_proj_mfma<<<dim3(2, 32, 8), 256, 0, stream>>>(midb, wpb, bproj, out);
}

// Round 4
// 226.733 us; speedup vs baseline: 1.9543x; 1.0555x over previous
//
#include <hip/hip_runtime.h>

#define NB 8
#define CC 256
#define HH 8
#define DD 32
#define LL 4096

typedef short v8s __attribute__((ext_vector_type(8)));
typedef float v4f __attribute__((ext_vector_type(4)));
typedef unsigned short v8u __attribute__((ext_vector_type(8)));
typedef unsigned short v4us __attribute__((ext_vector_type(4)));

__device__ __forceinline__ float4 ld4(const float* p) { return *(const float4*)p; }

// round-to-nearest-even fp32 -> bf16 (as ushort)
__device__ __forceinline__ unsigned short f2bf(float f) {
    union { float f; unsigned int u; } v; v.f = f;
    unsigned int r = (v.u + 0x7FFFu + ((v.u >> 16) & 1u)) >> 16;
    return (unsigned short)r;
}
__device__ __forceinline__ float bf2f(unsigned short u) {
    union { unsigned int u; float f; } v; v.u = ((unsigned int)u) << 16;
    return v.f;
}

// ---------------------------------------------------------------------------
// Convert fp32 -> bf16 (weights)
// ---------------------------------------------------------------------------
__global__ __launch_bounds__(256) void cvt_k(const float* __restrict__ s,
                                             unsigned short* __restrict__ d, int n)
{
    int i = blockIdx.x * 256 + threadIdx.x;
    if (i < n) d[i] = f2bf(s[i]);
}

// ---------------------------------------------------------------------------
// Transpose x[N,C,L] fp32 -> xb[N,L,C] bf16.
// ---------------------------------------------------------------------------
#define PADC 264
__global__ __launch_bounds__(256) void transpose_x_k(
    const float* __restrict__ x, unsigned short* __restrict__ xb)
{
    __shared__ unsigned short t[32][PADC];
    const int n = blockIdx.y;
    const int l0 = blockIdx.x * 32;
    const float* xn = x + (size_t)n * CC * LL;
    const int lam = threadIdx.x & 31;
    const int cb = threadIdx.x >> 5;
#pragma unroll
    for (int i = 0; i < 32; ++i) {
        int c = cb * 32 + i;
        t[lam][c] = f2bf(xn[(size_t)c * LL + l0 + lam]);
    }
    __syncthreads();
    unsigned short* dst = xb + ((size_t)n * LL + l0) * CC;
    const int tid = threadIdx.x;
#pragma unroll
    for (int i = 0; i < 4; ++i) {
        int f = i * 2048 + tid * 8;
        int lr = f >> 8;
        int c2 = f & 255;
        v8u val = *(const v8u*)&t[lr][c2];
        *(v8u*)(dst + f) = val;
    }
}

// ---------------------------------------------------------------------------
// Kernel 1: MFMA qkv GEMM, M=j (rows), N=l (cols).  Fused L2-norm for q/k.
// acc row axis (quad*4+reg) = 4 CONTIGUOUS j -> v4us bf16 packed stores.
// Norm over d: 8 in-reg squares (mi-pair x reg) + shfl_xor(16), shfl_xor(32).
// ---------------------------------------------------------------------------
__global__ __launch_bounds__(256) void gemm_qkv_mfma(
    const unsigned short* __restrict__ xb, const unsigned short* __restrict__ wqb,
    const float* __restrict__ bqkv,
    unsigned short* __restrict__ q, unsigned short* __restrict__ k,
    unsigned short* __restrict__ v)
{
    const int n  = blockIdx.z;
    const int j0 = blockIdx.x * 128;
    const int l0 = blockIdx.y * 128;
    const int tid = threadIdx.x;
    const int lane = tid & 63, wave = tid >> 6;
    const int wr = wave >> 1, wc = wave & 1;
    const int r = lane & 15, quad = lane >> 4;

    const unsigned short* abase = wqb + (size_t)(j0 + wr * 64 + r) * CC + quad * 8;
    const unsigned short* bbase = xb + (size_t)n * LL * CC
                                + (size_t)(l0 + wc * 64 + r) * CC + quad * 8;

    v4f acc[4][4];
#pragma unroll
    for (int mi = 0; mi < 4; ++mi)
#pragma unroll
        for (int nj = 0; nj < 4; ++nj) acc[mi][nj] = (v4f)(0.f);

    for (int c0 = 0; c0 < CC; c0 += 32) {
        v8s a[4], b[4];
#pragma unroll
        for (int mi = 0; mi < 4; ++mi) a[mi] = *(const v8s*)(abase + (size_t)mi * 16 * CC + c0);
#pragma unroll
        for (int nj = 0; nj < 4; ++nj) b[nj] = *(const v8s*)(bbase + (size_t)nj * 16 * CC + c0);
#pragma unroll
        for (int mi = 0; mi < 4; ++mi)
#pragma unroll
            for (int nj = 0; nj < 4; ++nj)
                acc[mi][nj] = __builtin_amdgcn_mfma_f32_16x16x32_bf16(a[mi], b[nj], acc[mi][nj], 0, 0, 0);
    }

    // D mapping: row j = quad*4+reg (+mi*16), col l = lane&15 (+nj*16)
    const int s = j0 >> 8;                    // 0=q 1=k 2=v, block-uniform
    unsigned short* base = (s == 0 ? q : (s == 1 ? k : v));

    float bias[4][4];
#pragma unroll
    for (int mi = 0; mi < 4; ++mi)
#pragma unroll
        for (int reg = 0; reg < 4; ++reg)
            bias[mi][reg] = bqkv[j0 + wr * 64 + mi * 16 + quad * 4 + reg];

    unsigned short* dstp[4];
#pragma unroll
    for (int mi = 0; mi < 4; ++mi) {
        int hh = ((j0 >> 5) + wr * 2 + (mi >> 1)) & 7;
        int d0 = (mi & 1) * 16 + quad * 4;
        dstp[mi] = base + (size_t)(n * HH + hh) * LL * DD + d0;
    }

    if (s < 2) {
#pragma unroll
        for (int nj = 0; nj < 4; ++nj) {
            float t[4][4];
            float ss0 = 0.f, ss1 = 0.f;
#pragma unroll
            for (int mi = 0; mi < 4; ++mi)
#pragma unroll
                for (int reg = 0; reg < 4; ++reg) {
                    float val = acc[mi][nj][reg] + bias[mi][reg];
                    t[mi][reg] = val;
                    if (mi < 2) ss0 += val * val; else ss1 += val * val;
                }
            ss0 += __shfl_xor(ss0, 16); ss0 += __shfl_xor(ss0, 32);
            ss1 += __shfl_xor(ss1, 16); ss1 += __shfl_xor(ss1, 32);
            float rn0 = rsqrtf(ss0), rn1 = rsqrtf(ss1);
            size_t l = (size_t)(l0 + wc * 64 + nj * 16 + r);
#pragma unroll
            for (int mi = 0; mi < 4; ++mi) {
                float rn = (mi < 2) ? rn0 : rn1;
                v4us pk;
#pragma unroll
                for (int reg = 0; reg < 4; ++reg) pk[reg] = f2bf(t[mi][reg] * rn);
                *(v4us*)(dstp[mi] + l * DD) = pk;
            }
        }
    } else {
#pragma unroll
        for (int nj = 0; nj < 4; ++nj) {
            size_t l = (size_t)(l0 + wc * 64 + nj * 16 + r);
#pragma unroll
            for (int mi = 0; mi < 4; ++mi) {
                v4us pk;
#pragma unroll
                for (int reg = 0; reg < 4; ++reg)
                    pk[reg] = f2bf(acc[mi][nj][reg] + bias[mi][reg]);
                *(v4us*)(dstp[mi] + l * DD) = pk;
            }
        }
    }
}

// ---------------------------------------------------------------------------
// Kernel 3: attn[n,h,d,e] = sum_l k[n,h,l,d] * v[n,h,l,e]   (bf16 in, fp32 acc)
// ---------------------------------------------------------------------------
__global__ __launch_bounds__(256) void attn_k(
    const unsigned short* __restrict__ k, const unsigned short* __restrict__ v,
    float* __restrict__ attn)
{
    __shared__ float red[4][1024];
    const int nh = blockIdx.y;
    const int wv = threadIdx.x >> 6;
    const int lane = threadIdx.x & 63;
    const int eg = lane & 7;
    const int dg = lane >> 3;
    const int l0 = blockIdx.x * 512 + wv * 128;
    const unsigned short* kb = k + (size_t)nh * LL * DD;
    const unsigned short* vb = v + (size_t)nh * LL * DD;
    float acc[4][4] = {};
#pragma unroll 4
    for (int l = l0; l < l0 + 128; ++l) {
        v4us k4 = *(const v4us*)(kb + (size_t)l * DD + dg * 4);
        v4us v4 = *(const v4us*)(vb + (size_t)l * DD + eg * 4);
        float ka[4] = {bf2f(k4[0]), bf2f(k4[1]), bf2f(k4[2]), bf2f(k4[3])};
        float va[4] = {bf2f(v4[0]), bf2f(v4[1]), bf2f(v4[2]), bf2f(v4[3])};
#pragma unroll
        for (int dp = 0; dp < 4; ++dp)
#pragma unroll
            for (int ep = 0; ep < 4; ++ep)
                acc[dp][ep] += ka[dp] * va[ep];
    }
#pragma unroll
    for (int dp = 0; dp < 4; ++dp)
#pragma unroll
        for (int ep = 0; ep < 4; ++ep)
            red[wv][(dg * 4 + dp) * 32 + eg * 4 + ep] = acc[dp][ep];
    __syncthreads();
    float* ap = attn + (size_t)nh * 1024;
    for (int i = threadIdx.x; i < 1024; i += 256)
        atomicAdd(&ap[i], red[0][i] + red[1][i] + red[2][i] + red[3][i]);
}

// ---------------------------------------------------------------------------
// Kernel 4: one block = 256 tokens of one (n,h); bf16 q/v in, bf16 mid out.
// ---------------------------------------------------------------------------
#define TOK 256
__global__ __launch_bounds__(256) void mid_k(
    const unsigned short* __restrict__ q, const unsigned short* __restrict__ v,
    const float* __restrict__ attn, const float* __restrict__ wd,
    unsigned short* __restrict__ midb)
{
    __shared__ float vt[TOK + 8][32];
    const int nh = blockIdx.y;
    const int n = nh >> 3, hh = nh & 7;
    const int l0 = blockIdx.x * TOK;
    const int tid = threadIdx.x;
    const int row = tid >> 5;
    const int e = tid & 31;
    const unsigned short* vb = v + (size_t)nh * LL * DD;

    for (int f = tid; f < (TOK + 8) * 32; f += 256) {
        int rr = f >> 5, ee = f & 31;
        int l = l0 - 4 + rr;
        vt[rr][ee] = (l >= 0 && l < LL) ? bf2f(vb[(size_t)l * DD + ee]) : 0.f;
    }

    float atc[32];
    const float* ap = attn + (size_t)nh * 1024 + e;
#pragma unroll
    for (int d = 0; d < 32; ++d) atc[d] = ap[d * 32];

    float wc[9];
#pragma unroll
    for (int r9 = 0; r9 < 9; ++r9) wc[r9] = wd[hh * 9 + r9];

    __syncthreads();

    const unsigned short* qb = q + (size_t)nh * LL * DD;
    unsigned short* ob = midb + ((size_t)n * LL) * CC + hh * DD + e;

    for (int it = 0; it < TOK / 8; ++it) {
        int lr = it * 8 + row;
        int l = l0 + lr;
        const unsigned short* qrow = qb + (size_t)l * DD;
        float s = 0.f;
#pragma unroll
        for (int d8 = 0; d8 < 4; ++d8) {
            v8u q8 = *(const v8u*)(qrow + d8 * 8);
#pragma unroll
            for (int jj = 0; jj < 8; ++jj)
                s += bf2f(q8[jj]) * atc[d8 * 8 + jj];
        }
        float t = 0.5f * vt[lr + 4][e] + 0.31830988618379067f * s;
        float ss = t * t;
#pragma unroll
        for (int off = 16; off; off >>= 1) ss += __shfl_xor(ss, off, 32);
        float o = t * rsqrtf(ss);
        float dv = 0.f;
#pragma unroll
        for (int r9 = 0; r9 < 9; ++r9) dv += wc[r9] * vt[lr + r9][e];
        ob[(size_t)l * CC] = f2bf(o + dv);
    }
}

// ---------------------------------------------------------------------------
// Kernel 5: MFMA proj GEMM (M=j, N=l), coalesced stores along l.
// ---------------------------------------------------------------------------
__global__ __launch_bounds__(256) void gemm_proj_mfma(
    const unsigned short* __restrict__ midb, const unsigned short* __restrict__ wpb,
    const float* __restrict__ bp, float* __restrict__ out)
{
    const int n  = blockIdx.z;
    const int j0 = blockIdx.x * 128;
    const int l0 = blockIdx.y * 128;
    const int tid = threadIdx.x;
    const int lane = tid & 63, wave = tid >> 6;
    const int wr = wave >> 1, wc = wave & 1;
    const int r = lane & 15, quad = lane >> 4;

    const unsigned short* abase = wpb + (size_t)(j0 + wr * 64 + r) * CC + quad * 8;
    const unsigned short* bbase = midb + (size_t)n * LL * CC
                                + (size_t)(l0 + wc * 64 + r) * CC + quad * 8;

    v4f acc[4][4];
#pragma unroll
    for (int mi = 0; mi < 4; ++mi)
#pragma unroll
        for (int nj = 0; nj < 4; ++nj) acc[mi][nj] = (v4f)(0.f);

    for (int c0 = 0; c0 < CC; c0 += 32) {
        v8s a[4], b[4];
#pragma unroll
        for (int mi = 0; mi < 4; ++mi) a[mi] = *(const v8s*)(abase + (size_t)mi * 16 * CC + c0);
#pragma unroll
        for (int nj = 0; nj < 4; ++nj) b[nj] = *(const v8s*)(bbase + (size_t)nj * 16 * CC + c0);
#pragma unroll
        for (int mi = 0; mi < 4; ++mi)
#pragma unroll
            for (int nj = 0; nj < 4; ++nj)
                acc[mi][nj] = __builtin_amdgcn_mfma_f32_16x16x32_bf16(a[mi], b[nj], acc[mi][nj], 0, 0, 0);
    }

#pragma unroll
    for (int mi = 0; mi < 4; ++mi)
#pragma unroll
        for (int reg = 0; reg < 4; ++reg) {
            int j = j0 + wr * 64 + mi * 16 + quad * 4 + reg;
            float bias = bp[j];
#pragma unroll
            for (int nj = 0; nj < 4; ++nj) {
                int l = l0 + wc * 64 + nj * 16 + r;
                out[((size_t)n * CC + j) * LL + l] = acc[mi][nj][reg] + bias;
            }
        }
}

// ---------------------------------------------------------------------------
extern "C" void kernel_launch(void* const* d_in, const int* in_sizes, int n_in,
                              void* d_out, int out_size, void* d_ws, size_t ws_size,
                              hipStream_t stream)
{
    const float* x     = (const float*)d_in[0];
    const float* wqkv  = (const float*)d_in[1];
    const float* bqkv  = (const float*)d_in[2];
    const float* wproj = (const float*)d_in[3];
    const float* bproj = (const float*)d_in[4];
    const float* wd    = (const float*)d_in[5];
    float* out = (float*)d_out;

    const size_t QKV = (size_t)NB * HH * LL * DD;       // 8388608 elems
    unsigned short* q = (unsigned short*)d_ws;
    unsigned short* k = q + QKV;
    unsigned short* v = k + QKV;
    float* attn = (float*)(v + QKV);                    // 65536 floats
    unsigned short* xb = (unsigned short*)(attn + (size_t)NB * HH * DD * DD);
    unsigned short* midb = xb;                          // disjoint live ranges
    unsigned short* wqb = xb + (size_t)NB * LL * CC;
    unsigned short* wpb = wqb + 3 * CC * CC;

    hipMemsetAsync(attn, 0, (size_t)NB * HH * DD * DD * sizeof(float), stream);

    cvt_k<<<768, 256, 0, stream>>>(wqkv, wqb, 3 * CC * CC);
    cvt_k<<<256, 256, 0, stream>>>(wproj, wpb, CC * CC);
    transpose_x_k<<<dim3(128, 8), 256, 0, stream>>>(x, xb);
    gemm_qkv_mfma<<<dim3(6, 32, 8), 256, 0, stream>>>(xb, wqb, bqkv, q, k, v);
    attn_k<<<dim3(8, 64), 256, 0, stream>>>(k, v, attn);
    mid_k<<<dim3(LL / TOK, 64), 256, 0, stream>>>(q, v, attn, wd, midb);
    gemm_proj_mfma<<<dim3(2, 32, 8), 256, 0, stream>>>(midb, wpb, bproj, out);
}